// Round 1
// baseline (966.239 us; speedup 1.0000x reference)
//
#include <hip/hip_runtime.h>
#include <math.h>

// Problem constants (fixed by the reference file)
#define DD 8192     // sketch dimension d
#define CC 768      // channels
#define SS 145      // sequence length
#define BB 32       // batch
#define NSLICE 8    // c-slices per b in K2
#define CSL (CC/NSLICE)

// ---------------------------------------------------------------------------
// K2: build per-batch Z vectors.
//   Zuu[b,d] = sum_{c,e} u[b,c]u[b,e] s1[c]s2[e] [h1[c]+h2[e] == d mod D]
//   Zcr[b,d] = sum_{c,e} (u[b,c]+u[b,e]) s1[c]s2[e] [...]
//   Z11[d]   = sum_{c,e} s1[c]s2[e] [...]
// where u[b,c] = b_sensor[c] + sum_n sensor[b,n] * W_sensor[c,n]
// Grid: BB*NSLICE blocks; each block owns one c-slice of one b, accumulates
// into LDS, then merges with global atomics (Z* pre-zeroed via memset).
// ---------------------------------------------------------------------------
__global__ __launch_bounds__(256) void k2_buildZ(
    const float* __restrict__ sensor, const float* __restrict__ Wsen,
    const float* __restrict__ bsen,
    const int* __restrict__ h1, const int* __restrict__ h2,
    const int* __restrict__ s1, const int* __restrict__ s2,
    float* __restrict__ Zuu, float* __restrict__ Zcr, float* __restrict__ Z11)
{
    __shared__ float Zl[DD];                 // 32 KB accumulator
    __shared__ float sens[64];
    __shared__ float u1[CC], u2[CC], s1f[CC], s2f[CC];
    __shared__ int   h1s[CC], h2s[CC];

    const int b     = blockIdx.x / NSLICE;
    const int slice = blockIdx.x % NSLICE;
    const int tid   = threadIdx.x;

    if (tid < 64) sens[tid] = sensor[b*64 + tid];
    __syncthreads();

    for (int c = tid; c < CC; c += 256) {
        float u = bsen[c];
        const float* w = Wsen + c*64;
        #pragma unroll 8
        for (int n = 0; n < 64; ++n) u += sens[n] * w[n];
        float f1 = (float)s1[c], f2 = (float)s2[c];
        u1[c] = u * f1; u2[c] = u * f2;
        s1f[c] = f1;    s2f[c] = f2;
        h1s[c] = h1[c]; h2s[c] = h2[c];
    }
    __syncthreads();

    const int c0 = slice * CSL;
    const int npass = (b == 0) ? 3 : 2;      // Z11 is b-independent: only b==0
    for (int pass = 0; pass < npass; ++pass) {
        for (int i = tid; i < DD; i += 256) Zl[i] = 0.f;
        __syncthreads();
        for (int c = c0; c < c0 + CSL; ++c) {
            const float A  = u1[c];
            const float Sc = s1f[c];
            const int   hc = h1s[c];
            for (int e = tid; e < CC; e += 256) {
                const int idx = (hc + h2s[e]) & (DD - 1);
                float val;
                if (pass == 0)      val = A * u2[e];
                else if (pass == 1) val = A * s2f[e] + Sc * u2[e];
                else                val = Sc * s2f[e];
                atomicAdd(&Zl[idx], val);
            }
        }
        __syncthreads();
        float* dst = (pass == 0) ? (Zuu + b*DD) : (pass == 1) ? (Zcr + b*DD) : Z11;
        for (int i = tid; i < DD; i += 256) {
            float v = Zl[i];
            if (v != 0.f) atomicAdd(&dst[i], v);
        }
        __syncthreads();
    }
}

// ---------------------------------------------------------------------------
// K3: one block per (b,s). Combine Z into LDS, then the bilinear form
//   ip = sum_{c,e} a1[c]*a2[e]*Zf[(h1[c]+h2[e]) & (D-1)],
// with a1/a2 = (E[b,s,:]+tok1)*s1/s2. 3 channels per thread kept in regs;
// e-loop reads a packed (a2,h2) float2 broadcast from LDS.
// Writes bp[b,s] = sign(ip)*sqrt(|ip|+1e-5).
// ---------------------------------------------------------------------------
__global__ __launch_bounds__(256) void k3_qform(
    const float* __restrict__ E, const float* __restrict__ tok,
    const int* __restrict__ h1, const int* __restrict__ h2,
    const int* __restrict__ s1, const int* __restrict__ s2,
    const float* __restrict__ Ws2, const float* __restrict__ bs2,
    const float* __restrict__ Zuu, const float* __restrict__ Zcr,
    const float* __restrict__ Z11, float* __restrict__ bp)
{
    __shared__ float  Zf[DD];                // 32 KB
    __shared__ float2 ea[CC];                // 6 KB: (a2[e], bits(h2[e]))
    __shared__ float  red[4];

    const int si  = blockIdx.x;              // s index
    const int b   = blockIdx.y;
    const int tid = threadIdx.x;

    const float w2 = Ws2[si], bb = bs2[si];
    const float al = w2*w2, be = w2*bb, ga = bb*bb;
    const float* Zu = Zuu + b*DD;
    const float* Zc = Zcr + b*DD;
    for (int i = tid; i < DD; i += 256)
        Zf[i] = al*Zu[i] + be*Zc[i] + ga*Z11[i];

    float a1r[3]; int h1r[3];
    const float* Erow = E + (size_t)(b*SS + si) * CC;
    #pragma unroll
    for (int k = 0; k < 3; ++k) {
        int c = tid + k*256;
        float x = Erow[c] + tok[CC + c];     // tok_emb[1,:]
        a1r[k] = x * (float)s1[c];
        h1r[k] = h1[c];
        ea[c]  = make_float2(x * (float)s2[c], __int_as_float(h2[c]));
    }
    __syncthreads();

    float acc0 = 0.f, acc1 = 0.f, acc2 = 0.f;
    #pragma unroll 4
    for (int e = 0; e < CC; ++e) {
        float2 p  = ea[e];
        float a2e = p.x;
        int   he  = __float_as_int(p.y);
        acc0 += a1r[0]*a2e * Zf[(h1r[0]+he) & (DD-1)];
        acc1 += a1r[1]*a2e * Zf[(h1r[1]+he) & (DD-1)];
        acc2 += a1r[2]*a2e * Zf[(h1r[2]+he) & (DD-1)];
    }

    float v = acc0 + acc1 + acc2;
    #pragma unroll
    for (int off = 32; off > 0; off >>= 1) v += __shfl_down(v, off, 64);
    if ((tid & 63) == 0) red[tid >> 6] = v;
    __syncthreads();
    if (tid == 0) {
        float ip = red[0] + red[1] + red[2] + red[3];
        float sg = (ip > 0.f) ? 1.f : ((ip < 0.f) ? -1.f : 0.f);
        bp[b*SS + si] = sg * sqrtf(fabsf(ip) + 1e-5f);
    }
}

// ---------------------------------------------------------------------------
// K4: per-b signed-sqrt vector is already in bp; L2-normalize over s and
// project with W_out, add b_out. One block per b.
// ---------------------------------------------------------------------------
__global__ __launch_bounds__(256) void k4_final(
    const float* __restrict__ bp, const float* __restrict__ Wout,
    const float* __restrict__ bout, float* __restrict__ out)
{
    __shared__ float red[8];
    const int b = blockIdx.x, tid = threadIdx.x;
    float v = 0.f, w = 0.f;
    if (tid < SS) { v = bp[b*SS + tid]; w = v * Wout[tid]; }
    float sq = v * v;
    #pragma unroll
    for (int off = 32; off > 0; off >>= 1) {
        sq += __shfl_down(sq, off, 64);
        w  += __shfl_down(w,  off, 64);
    }
    if ((tid & 63) == 0) { red[tid >> 6] = sq; red[4 + (tid >> 6)] = w; }
    __syncthreads();
    if (tid == 0) {
        float ssq  = red[0] + red[1] + red[2] + red[3];
        float sw   = red[4] + red[5] + red[6] + red[7];
        float norm = fmaxf(sqrtf(ssq), 1e-12f);
        out[b] = sw / norm + bout[0];
    }
}

// ---------------------------------------------------------------------------
extern "C" void kernel_launch(void* const* d_in, const int* in_sizes, int n_in,
                              void* d_out, int out_size, void* d_ws, size_t ws_size,
                              hipStream_t stream) {
    const float* sensor = (const float*)d_in[0];
    const float* E      = (const float*)d_in[1];
    // d_in[2] image_masks: shape-only, unused
    const int*   h1     = (const int*)d_in[3];
    const int*   h2     = (const int*)d_in[4];
    const int*   s1     = (const int*)d_in[5];
    const int*   s2     = (const int*)d_in[6];
    // d_in[7] d (=8192): hard-coded
    const float* Wsen   = (const float*)d_in[8];
    const float* bsen   = (const float*)d_in[9];
    const float* Ws2    = (const float*)d_in[10];
    const float* bs2    = (const float*)d_in[11];
    const float* Wout   = (const float*)d_in[12];
    const float* bout   = (const float*)d_in[13];
    const float* tok    = (const float*)d_in[14];
    float* out = (float*)d_out;

    float* ws  = (float*)d_ws;
    float* Zuu = ws;                          // BB*DD floats
    float* Zcr = ws + (size_t)BB*DD;          // BB*DD floats
    float* Z11 = ws + (size_t)2*BB*DD;        // DD floats
    float* bp  = ws + (size_t)2*BB*DD + DD;   // BB*SS floats
    // total ws use: (2*32*8192 + 8192 + 32*145)*4 B ~= 2.05 MB

    hipMemsetAsync(ws, 0, ((size_t)2*BB*DD + DD) * sizeof(float), stream);

    k2_buildZ<<<dim3(BB*NSLICE), dim3(256), 0, stream>>>(
        sensor, Wsen, bsen, h1, h2, s1, s2, Zuu, Zcr, Z11);

    k3_qform<<<dim3(SS, BB), dim3(256), 0, stream>>>(
        E, tok, h1, h2, s1, s2, Ws2, bs2, Zuu, Zcr, Z11, bp);

    k4_final<<<dim3(BB), dim3(256), 0, stream>>>(bp, Wout, bout, out);
}